// Round 20
// baseline (57.437 us; speedup 1.0000x reference)
//
#include <hip/hip_runtime.h>

// GraphPositionalEncoding: degree-table PE + k-step return probabilities.
//
// Symmetric reformulation: T = A D^{-1} is similar to S = D^{-1/2} A D^{-1/2},
// so diag(T^k) = diag(S^k). With stored panel P_m := D^{-1/2} S^m E_J (J = 128
// start columns) and W := A * P_m (0/1 adjacency, exact in fp16 -> MFMA):
//   P_{m+1} = dinv ∘ W
//   diag(S^{2m+1})[j] = sum_r P_m[r,j] * W[r,j]
//   diag(S^{2m+2})[j] = sum_r dinv_r * W[r,j]^2
// K=8 needs only P_1..P_3 and 3 MFMA matmuls of 256x256x128 per block.
//
// R20: merged dot+write phase. Waves' dot-reads and P-writes touch only their
// OWN Zt rows (only the MFMA loop reads all rows), so the dot pass legally
// moves after the barrier and fuses with the write: one address calc, read oh,
// accumulate cross/sq, pack dinv*W, store to the same address. Same barrier
// count, one full addr-calc pass + loop overhead removed per step. mm=3 stays
// dot-only. Rest = R19 (nibble-LUT A-expansion, fused epilogue).

#define NPG 256
#define HID 256
#define KD  8

typedef _Float16 f16x8 __attribute__((ext_vector_type(8)));
typedef _Float16 f16x4 __attribute__((ext_vector_type(4)));
typedef float    f32x4 __attribute__((ext_vector_type(4)));
typedef unsigned u32x4 __attribute__((ext_vector_type(4)));
typedef unsigned u32x2 __attribute__((ext_vector_type(2)));

static __device__ __forceinline__ unsigned pkh2(float a, float b) {
    unsigned short lo = __builtin_bit_cast(unsigned short, (_Float16)a);
    unsigned short hi = __builtin_bit_cast(unsigned short, (_Float16)b);
    return (unsigned)lo | ((unsigned)hi << 16);
}

__global__ __launch_bounds__(512, 2) void k_rw2(const int* __restrict__ ei, int epg, int nE,
                                                const float* __restrict__ table,
                                                const float* __restrict__ w,
                                                const float* __restrict__ b,
                                                float* __restrict__ out) {
    __shared__ unsigned int bits[NPG * 8];            // 8 KB bitmask; reused as dots[8][128]
    __shared__ float diA[NPG];                        // 1 KB 1/deg
    __shared__ __align__(16) _Float16 Zt[128 * 256];  // 64 KB P panel, [j][c], slot-swizzled
    __shared__ int cnt[128];                          // 0.5 KB raw in-degree (own half)
    __shared__ __align__(8) unsigned lutAB[16][2];    // 128 B nibble -> 2x fp16-pair LUT
    float (*dots)[128] = (float(*)[128])bits;         // alias: valid after last bits read

    const int g    = blockIdx.x >> 1;
    const int jb   = (blockIdx.x & 1) << 7;
    const int t    = threadIdx.x;
    const int lane = t & 63;
    const int wid  = t >> 6;                          // 8 waves
    const int wr   = wid >> 1;                        // 0..3 row-group (64 rows each)
    const int wj   = wid & 1;                         // 0..1 col-group (64 cols each)
    const int l15  = lane & 15;
    const int q    = lane >> 4;

    #pragma unroll
    for (int i = 0; i < 4; ++i) bits[t + 512 * i] = 0u;
    if (t < 128) cnt[t] = 0;
    if (t < 16) {                                     // LUT[n] = {pk(b0,b1), pk(b2,b3)}
        lutAB[t][0] = ((t & 1u) ? 0x3C00u : 0u) | ((t & 2u) ? 0x3C000000u : 0u);
        lutAB[t][1] = ((t & 4u) ? 0x3C00u : 0u) | ((t & 8u) ? 0x3C000000u : 0u);
    }
    __syncthreads();

    const int* sp = ei + (size_t)g * epg;
    const int* dp = ei + (size_t)nE + (size_t)g * epg;
    for (int e = t; e < epg; e += 512) {
        int ls = sp[e] & (NPG - 1);
        int ld = dp[e] & (NPG - 1);
        atomicOr(&bits[ls * 8 + (ld >> 5)], 1u << (ld & 31));
        atomicOr(&bits[ld * 8 + (ls >> 5)], 1u << (ls & 31));
        if ((ld & 128) == jb) atomicAdd(&cnt[ld & 127], 1); // own half only
    }
    __syncthreads();

    if (t < NPG) {
        int dg = 0;
        #pragma unroll
        for (int w8 = 0; w8 < 8; ++w8) dg += __popc(bits[t * 8 + w8]);
        diA[t] = dg ? 1.f / (float)dg : 0.f;
    }
    __syncthreads();

    // ---- build P1[c,j] = dinv_c * s_j * a(c,j) into Zt; k2 partial in regs ----
    const int jcol = t & 127;                         // both passes share this column
    const int jg   = jb + jcol;
    const float dij = diA[jg];
    float accsum = 0.f;
    {
        float sj = sqrtf(dij);
        #pragma unroll
        for (int pass = 0; pass < 2; ++pass) {
            int wd = (t >> 7) + pass * 4;
            unsigned word = bits[jg * 8 + wd];
            #pragma unroll
            for (int sl = 0; sl < 4; ++sl) {
                int c0 = wd * 32 + sl * 8;
                unsigned byte = (word >> (sl * 8)) & 0xFFu;
                float4 d0 = *(const float4*)(diA + c0);
                float4 d1 = *(const float4*)(diA + c0 + 4);
                float dv0 = (byte & 1u)   ? d0.x : 0.f;
                float dv1 = (byte & 2u)   ? d0.y : 0.f;
                float dv2 = (byte & 4u)   ? d0.z : 0.f;
                float dv3 = (byte & 8u)   ? d0.w : 0.f;
                float dv4 = (byte & 16u)  ? d1.x : 0.f;
                float dv5 = (byte & 32u)  ? d1.y : 0.f;
                float dv6 = (byte & 64u)  ? d1.z : 0.f;
                float dv7 = (byte & 128u) ? d1.w : 0.f;
                accsum += dv0 + dv1 + dv2 + dv3 + dv4 + dv5 + dv6 + dv7;
                u32x4 pw;
                pw.x = pkh2(dv0 * sj, dv1 * sj);
                pw.y = pkh2(dv2 * sj, dv3 * sj);
                pw.z = pkh2(dv4 * sj, dv5 * sj);
                pw.w = pkh2(dv6 * sj, dv7 * sj);
                int slp = (wd * 4 + sl) ^ (jcol & 7);
                *(u32x4*)(Zt + jcol * 256 + slp * 8) = pw;
            }
        }
    }
    // k1 = dinv_j if self-loop (read bits before alias flip)
    float k1v = 0.f;
    if (t < 128) {
        int jg2 = jb + t;
        k1v = ((bits[jg2 * 8 + (jg2 >> 5)] >> (jg2 & 31)) & 1u) ? diA[jg2] : 0.f;
    }

    // per-lane packed A bytes: ab[ks] byte rr covers row wr*64+rr*16+l15, k-bits ks*32+q*8..+8
    unsigned ab[8];
    #pragma unroll
    for (int ks = 0; ks < 8; ++ks) {
        unsigned v = 0;
        #pragma unroll
        for (int rr = 0; rr < 4; ++rr) {
            int r = wr * 64 + rr * 16 + l15;
            v |= ((bits[r * 8 + ks] >> (q * 8)) & 0xFFu) << (rr * 8);
        }
        ab[ks] = v;
    }
    __syncthreads();                                  // all bits reads complete

    // ---- alias flip: zero dots (over bits), then flush register partials ----
    ((float*)bits)[t] = 0.f;
    ((float*)bits)[t + 512] = 0.f;
    __syncthreads();
    atomicAdd(&dots[1][jcol], dij * accsum);
    if (t < 128) dots[0][t] = k1v;

    // ---- 3 MFMA steps, single pass: 4 row-tiles x 4 col-tiles per wave ----
    for (int mm = 1; mm <= 3; ++mm) {
        f32x4 acc[4][4];
        #pragma unroll
        for (int rr = 0; rr < 4; ++rr)
            #pragma unroll
            for (int jj = 0; jj < 4; ++jj)
                acc[rr][jj] = (f32x4){0.f, 0.f, 0.f, 0.f};

        #pragma unroll
        for (int ks = 0; ks < 8; ++ks) {
            f16x8 af[4];
            #pragma unroll
            for (int rr = 0; rr < 4; ++rr) {
                unsigned byte = (ab[ks] >> (rr * 8)) & 0xFFu;
                u32x2 lo = *(const u32x2*)(&lutAB[byte & 15u][0]);
                u32x2 hi = *(const u32x2*)(&lutAB[byte >> 4][0]);
                u32x4 uu = {lo.x, lo.y, hi.x, hi.y};
                af[rr] = __builtin_bit_cast(f16x8, uu);
            }
            #pragma unroll
            for (int jj = 0; jj < 4; ++jj) {
                int jloc = wj * 64 + jj * 16 + l15;
                int slp = (ks * 4 + q) ^ (jloc & 7);
                f16x8 bf = __builtin_bit_cast(f16x8, *(const u32x4*)(Zt + jloc * 256 + slp * 8));
                #pragma unroll
                for (int rr = 0; rr < 4; ++rr)
                    acc[rr][jj] = __builtin_amdgcn_mfma_f32_16x16x32_f16(af[rr], bf, acc[rr][jj], 0, 0, 0);
            }
        }

        // merged dot(+write): own rows only. Barrier first when overwriting so
        // all waves' B-reads of P_m are complete; reads of own rows stay safe
        // because each wave writes only its own rows.
        if (mm < 3) __syncthreads();

        float c0 = 0.f, c1 = 0.f, c2 = 0.f, c3 = 0.f;
        float s0 = 0.f, s1 = 0.f, s2 = 0.f, s3 = 0.f;
        #pragma unroll
        for (int rr = 0; rr < 4; ++rr) {
            int r0 = wr * 64 + rr * 16 + q * 4;
            float4 di4 = *(const float4*)(diA + r0);
            int slot = (wr * 4 + rr) * 2 + (q >> 1);
            #pragma unroll
            for (int jj = 0; jj < 4; ++jj) {
                int jloc = wj * 64 + jj * 16 + l15;
                int slp = slot ^ (jloc & 7);
                _Float16* addr = Zt + jloc * 256 + slp * 8 + (q & 1) * 4;
                f16x4 oh = __builtin_bit_cast(f16x4, *(const u32x2*)addr);
                f32x4 W = acc[rr][jj];
                float cc = (float)oh.x * W[0] + (float)oh.y * W[1] +
                           (float)oh.z * W[2] + (float)oh.w * W[3];
                float ss = di4.x * W[0] * W[0] + di4.y * W[1] * W[1] +
                           di4.z * W[2] * W[2] + di4.w * W[3] * W[3];
                if (jj == 0) { c0 += cc; s0 += ss; }
                else if (jj == 1) { c1 += cc; s1 += ss; }
                else if (jj == 2) { c2 += cc; s2 += ss; }
                else { c3 += cc; s3 += ss; }
                if (mm < 3) {                         // write new P to the same address
                    u32x2 nw;
                    nw.x = pkh2(di4.x * W[0], di4.y * W[1]);
                    nw.y = pkh2(di4.z * W[2], di4.w * W[3]);
                    *(u32x2*)addr = nw;
                }
            }
        }
        // pre-reduce across q (lanes ^16, ^32) -> only q==0 lanes hit LDS atomics
        c0 += __shfl_xor(c0, 16); c0 += __shfl_xor(c0, 32);
        s0 += __shfl_xor(s0, 16); s0 += __shfl_xor(s0, 32);
        c1 += __shfl_xor(c1, 16); c1 += __shfl_xor(c1, 32);
        s1 += __shfl_xor(s1, 16); s1 += __shfl_xor(s1, 32);
        c2 += __shfl_xor(c2, 16); c2 += __shfl_xor(c2, 32);
        s2 += __shfl_xor(s2, 16); s2 += __shfl_xor(s2, 32);
        c3 += __shfl_xor(c3, 16); c3 += __shfl_xor(c3, 32);
        s3 += __shfl_xor(s3, 16); s3 += __shfl_xor(s3, 32);
        if (q == 0) {
            int j0 = wj * 64 + l15;
            atomicAdd(&dots[2 * mm][j0],      c0);
            atomicAdd(&dots[2 * mm + 1][j0],  s0);
            atomicAdd(&dots[2 * mm][j0 + 16], c1);
            atomicAdd(&dots[2 * mm + 1][j0 + 16], s1);
            atomicAdd(&dots[2 * mm][j0 + 32], c2);
            atomicAdd(&dots[2 * mm + 1][j0 + 32], s2);
            atomicAdd(&dots[2 * mm][j0 + 48], c3);
            atomicAdd(&dots[2 * mm + 1][j0 + 48], s3);
        }
        if (mm < 3) __syncthreads();                  // new P visible to next MFMA
    }

    // ---- hoisted epilogue constants: issue before the final barrier ----
    const int h = lane << 2;                          // column quad owned by lane
    float4 w00 = *(const float4*)(w + (size_t)(h + 0) * KD);
    float4 w01 = *(const float4*)(w + (size_t)(h + 0) * KD + 4);
    float4 w10 = *(const float4*)(w + (size_t)(h + 1) * KD);
    float4 w11 = *(const float4*)(w + (size_t)(h + 1) * KD + 4);
    float4 w20 = *(const float4*)(w + (size_t)(h + 2) * KD);
    float4 w21 = *(const float4*)(w + (size_t)(h + 2) * KD + 4);
    float4 w30 = *(const float4*)(w + (size_t)(h + 3) * KD);
    float4 w31 = *(const float4*)(w + (size_t)(h + 3) * KD + 4);
    float4 bb  = *(const float4*)(b + h);
    __syncthreads();

    // ---- fused epilogue, 1-deep pipelined: out = table[deg] + dots·w^T + b ----
    {
        int j = wid;                                  // 16 nodes per wave, stride 8
        int dgc = cnt[j]; dgc = dgc < 255 ? dgc : 255;
        float4 pe = *(const float4*)(table + (size_t)dgc * HID + h);
        for (; j < 128; j += 8) {
            int jn = j + 8;
            float4 pen = {};
            if (jn < 128) {                           // prefetch next node's gather
                int dgn = cnt[jn]; dgn = dgn < 255 ? dgn : 255;
                pen = *(const float4*)(table + (size_t)dgn * HID + h);
            }
            float r0x = dots[0][j], r0y = dots[1][j], r0z = dots[2][j], r0w = dots[3][j];
            float r1x = dots[4][j], r1y = dots[5][j], r1z = dots[6][j], r1w = dots[7][j];
            float o0 = r0x * w00.x + r0y * w00.y + r0z * w00.z + r0w * w00.w +
                       r1x * w01.x + r1y * w01.y + r1z * w01.z + r1w * w01.w;
            float o1 = r0x * w10.x + r0y * w10.y + r0z * w10.z + r0w * w10.w +
                       r1x * w11.x + r1y * w11.y + r1z * w11.z + r1w * w11.w;
            float o2 = r0x * w20.x + r0y * w20.y + r0z * w20.z + r0w * w20.w +
                       r1x * w21.x + r1y * w21.y + r1z * w21.z + r1w * w21.w;
            float o3 = r0x * w30.x + r0y * w30.y + r0z * w30.z + r0w * w30.w +
                       r1x * w31.x + r1y * w31.y + r1z * w31.z + r1w * w31.w;
            f32x4 res = {pe.x + o0 + bb.x, pe.y + o1 + bb.y,
                         pe.z + o2 + bb.z, pe.w + o3 + bb.w};
            size_t node = (size_t)g * NPG + jb + j;
            *(f32x4*)(out + node * HID + h) = res;    // cached store: drain via L2
            pe = pen;
        }
    }
}

extern "C" void kernel_launch(void* const* d_in, const int* in_sizes, int n_in,
                              void* d_out, int out_size, void* d_ws, size_t ws_size,
                              hipStream_t stream) {
    const int* ei      = (const int*)d_in[1];
    const float* table = (const float*)d_in[3];
    const float* rw_w  = (const float*)d_in[4];
    const float* rw_b  = (const float*)d_in[5];
    float* out         = (float*)d_out;

    const int nNodes = in_sizes[2];
    const int nE     = in_sizes[1] / 2;
    const int B      = nNodes / NPG;
    const int epg    = nE / B;

    k_rw2<<<B * 2, 512, 0, stream>>>(ei, epg, nE, table, rw_w, rw_b, out);
}

// Round 21
// 56.572 us; speedup vs baseline: 1.0153x; 1.0153x over previous
//
#include <hip/hip_runtime.h>

// GraphPositionalEncoding: degree-table PE + k-step return probabilities.
//
// Symmetric reformulation: T = A D^{-1} is similar to S = D^{-1/2} A D^{-1/2},
// so diag(T^k) = diag(S^k). With stored panel P_m := D^{-1/2} S^m E_J (J = 128
// start columns) and W := A * P_m (0/1 adjacency, exact in fp16 -> MFMA):
//   P_{m+1} = dinv ∘ W
//   diag(S^{2m+1})[j] = sum_r P_m[r,j] * W[r,j]
//   diag(S^{2m+2})[j] = sum_r dinv_r * W[r,j]^2
// K=8 needs only P_1..P_3 and 3 MFMA matmuls of 256x256x128 per block.
//
// R21 (final): restore R19 verbatim — the best verified state (56.8 us).
// R20's merged dot+write was neutral (latency-bound at 1 block/CU; saved
// VALU no longer converts to time). Ladder: 255 -> 56.8 us. Remaining
// imbalance (MFMA 16% / VALU 31% / HBM 15%) is wave-latency exposure at
// toolchain-pinned residency — structural, falsified across R13-R17.

#define NPG 256
#define HID 256
#define KD  8

typedef _Float16 f16x8 __attribute__((ext_vector_type(8)));
typedef _Float16 f16x4 __attribute__((ext_vector_type(4)));
typedef float    f32x4 __attribute__((ext_vector_type(4)));
typedef unsigned u32x4 __attribute__((ext_vector_type(4)));
typedef unsigned u32x2 __attribute__((ext_vector_type(2)));

static __device__ __forceinline__ unsigned pkh2(float a, float b) {
    unsigned short lo = __builtin_bit_cast(unsigned short, (_Float16)a);
    unsigned short hi = __builtin_bit_cast(unsigned short, (_Float16)b);
    return (unsigned)lo | ((unsigned)hi << 16);
}

__global__ __launch_bounds__(512, 2) void k_rw2(const int* __restrict__ ei, int epg, int nE,
                                                const float* __restrict__ table,
                                                const float* __restrict__ w,
                                                const float* __restrict__ b,
                                                float* __restrict__ out) {
    __shared__ unsigned int bits[NPG * 8];            // 8 KB bitmask; reused as dots[8][128]
    __shared__ float diA[NPG];                        // 1 KB 1/deg
    __shared__ __align__(16) _Float16 Zt[128 * 256];  // 64 KB P panel, [j][c], slot-swizzled
    __shared__ int cnt[128];                          // 0.5 KB raw in-degree (own half)
    __shared__ __align__(8) unsigned lutAB[16][2];    // 128 B nibble -> 2x fp16-pair LUT
    float (*dots)[128] = (float(*)[128])bits;         // alias: valid after last bits read

    const int g    = blockIdx.x >> 1;
    const int jb   = (blockIdx.x & 1) << 7;
    const int t    = threadIdx.x;
    const int lane = t & 63;
    const int wid  = t >> 6;                          // 8 waves
    const int wr   = wid >> 1;                        // 0..3 row-group (64 rows each)
    const int wj   = wid & 1;                         // 0..1 col-group (64 cols each)
    const int l15  = lane & 15;
    const int q    = lane >> 4;

    #pragma unroll
    for (int i = 0; i < 4; ++i) bits[t + 512 * i] = 0u;
    if (t < 128) cnt[t] = 0;
    if (t < 16) {                                     // LUT[n] = {pk(b0,b1), pk(b2,b3)}
        lutAB[t][0] = ((t & 1u) ? 0x3C00u : 0u) | ((t & 2u) ? 0x3C000000u : 0u);
        lutAB[t][1] = ((t & 4u) ? 0x3C00u : 0u) | ((t & 8u) ? 0x3C000000u : 0u);
    }
    __syncthreads();

    const int* sp = ei + (size_t)g * epg;
    const int* dp = ei + (size_t)nE + (size_t)g * epg;
    for (int e = t; e < epg; e += 512) {
        int ls = sp[e] & (NPG - 1);
        int ld = dp[e] & (NPG - 1);
        atomicOr(&bits[ls * 8 + (ld >> 5)], 1u << (ld & 31));
        atomicOr(&bits[ld * 8 + (ls >> 5)], 1u << (ls & 31));
        if ((ld & 128) == jb) atomicAdd(&cnt[ld & 127], 1); // own half only
    }
    __syncthreads();

    if (t < NPG) {
        int dg = 0;
        #pragma unroll
        for (int w8 = 0; w8 < 8; ++w8) dg += __popc(bits[t * 8 + w8]);
        diA[t] = dg ? 1.f / (float)dg : 0.f;
    }
    __syncthreads();

    // ---- build P1[c,j] = dinv_c * s_j * a(c,j) into Zt; k2 partial in regs ----
    const int jcol = t & 127;                         // both passes share this column
    const int jg   = jb + jcol;
    const float dij = diA[jg];
    float accsum = 0.f;
    {
        float sj = sqrtf(dij);
        #pragma unroll
        for (int pass = 0; pass < 2; ++pass) {
            int wd = (t >> 7) + pass * 4;
            unsigned word = bits[jg * 8 + wd];
            #pragma unroll
            for (int sl = 0; sl < 4; ++sl) {
                int c0 = wd * 32 + sl * 8;
                unsigned byte = (word >> (sl * 8)) & 0xFFu;
                float4 d0 = *(const float4*)(diA + c0);
                float4 d1 = *(const float4*)(diA + c0 + 4);
                float dv0 = (byte & 1u)   ? d0.x : 0.f;
                float dv1 = (byte & 2u)   ? d0.y : 0.f;
                float dv2 = (byte & 4u)   ? d0.z : 0.f;
                float dv3 = (byte & 8u)   ? d0.w : 0.f;
                float dv4 = (byte & 16u)  ? d1.x : 0.f;
                float dv5 = (byte & 32u)  ? d1.y : 0.f;
                float dv6 = (byte & 64u)  ? d1.z : 0.f;
                float dv7 = (byte & 128u) ? d1.w : 0.f;
                accsum += dv0 + dv1 + dv2 + dv3 + dv4 + dv5 + dv6 + dv7;
                u32x4 pw;
                pw.x = pkh2(dv0 * sj, dv1 * sj);
                pw.y = pkh2(dv2 * sj, dv3 * sj);
                pw.z = pkh2(dv4 * sj, dv5 * sj);
                pw.w = pkh2(dv6 * sj, dv7 * sj);
                int slp = (wd * 4 + sl) ^ (jcol & 7);
                *(u32x4*)(Zt + jcol * 256 + slp * 8) = pw;
            }
        }
    }
    // k1 = dinv_j if self-loop (read bits before alias flip)
    float k1v = 0.f;
    if (t < 128) {
        int jg2 = jb + t;
        k1v = ((bits[jg2 * 8 + (jg2 >> 5)] >> (jg2 & 31)) & 1u) ? diA[jg2] : 0.f;
    }

    // per-lane packed A bytes: ab[ks] byte rr covers row wr*64+rr*16+l15, k-bits ks*32+q*8..+8
    unsigned ab[8];
    #pragma unroll
    for (int ks = 0; ks < 8; ++ks) {
        unsigned v = 0;
        #pragma unroll
        for (int rr = 0; rr < 4; ++rr) {
            int r = wr * 64 + rr * 16 + l15;
            v |= ((bits[r * 8 + ks] >> (q * 8)) & 0xFFu) << (rr * 8);
        }
        ab[ks] = v;
    }
    __syncthreads();                                  // all bits reads complete

    // ---- alias flip: zero dots (over bits), then flush register partials ----
    ((float*)bits)[t] = 0.f;
    ((float*)bits)[t + 512] = 0.f;
    __syncthreads();
    atomicAdd(&dots[1][jcol], dij * accsum);
    if (t < 128) dots[0][t] = k1v;

    // ---- 3 MFMA steps, single pass: 4 row-tiles x 4 col-tiles per wave ----
    for (int mm = 1; mm <= 3; ++mm) {
        f32x4 acc[4][4];
        #pragma unroll
        for (int rr = 0; rr < 4; ++rr)
            #pragma unroll
            for (int jj = 0; jj < 4; ++jj)
                acc[rr][jj] = (f32x4){0.f, 0.f, 0.f, 0.f};

        #pragma unroll
        for (int ks = 0; ks < 8; ++ks) {
            f16x8 af[4];
            #pragma unroll
            for (int rr = 0; rr < 4; ++rr) {
                unsigned byte = (ab[ks] >> (rr * 8)) & 0xFFu;
                u32x2 lo = *(const u32x2*)(&lutAB[byte & 15u][0]);
                u32x2 hi = *(const u32x2*)(&lutAB[byte >> 4][0]);
                u32x4 uu = {lo.x, lo.y, hi.x, hi.y};
                af[rr] = __builtin_bit_cast(f16x8, uu);
            }
            #pragma unroll
            for (int jj = 0; jj < 4; ++jj) {
                int jloc = wj * 64 + jj * 16 + l15;
                int slp = (ks * 4 + q) ^ (jloc & 7);
                f16x8 bf = __builtin_bit_cast(f16x8, *(const u32x4*)(Zt + jloc * 256 + slp * 8));
                #pragma unroll
                for (int rr = 0; rr < 4; ++rr)
                    acc[rr][jj] = __builtin_amdgcn_mfma_f32_16x16x32_f16(af[rr], bf, acc[rr][jj], 0, 0, 0);
            }
        }

        // dots: cross = sum_r oldP*W, sq = sum_r dinv*W^2  (read old P in place)
        float c0 = 0.f, c1 = 0.f, c2 = 0.f, c3 = 0.f;
        float s0 = 0.f, s1 = 0.f, s2 = 0.f, s3 = 0.f;
        #pragma unroll
        for (int rr = 0; rr < 4; ++rr) {
            int r0 = wr * 64 + rr * 16 + q * 4;
            float4 di4 = *(const float4*)(diA + r0);
            int slot = (wr * 4 + rr) * 2 + (q >> 1);
            #pragma unroll
            for (int jj = 0; jj < 4; ++jj) {
                int jloc = wj * 64 + jj * 16 + l15;
                int slp = slot ^ (jloc & 7);
                f16x4 oh = __builtin_bit_cast(f16x4, *(const u32x2*)(Zt + jloc * 256 + slp * 8 + (q & 1) * 4));
                f32x4 W = acc[rr][jj];
                float cc = (float)oh.x * W[0] + (float)oh.y * W[1] +
                           (float)oh.z * W[2] + (float)oh.w * W[3];
                float ss = di4.x * W[0] * W[0] + di4.y * W[1] * W[1] +
                           di4.z * W[2] * W[2] + di4.w * W[3] * W[3];
                if (jj == 0) { c0 += cc; s0 += ss; }
                else if (jj == 1) { c1 += cc; s1 += ss; }
                else if (jj == 2) { c2 += cc; s2 += ss; }
                else { c3 += cc; s3 += ss; }
            }
        }
        // pre-reduce across q (lanes ^16, ^32) -> only q==0 lanes hit LDS atomics
        c0 += __shfl_xor(c0, 16); c0 += __shfl_xor(c0, 32);
        s0 += __shfl_xor(s0, 16); s0 += __shfl_xor(s0, 32);
        c1 += __shfl_xor(c1, 16); c1 += __shfl_xor(c1, 32);
        s1 += __shfl_xor(s1, 16); s1 += __shfl_xor(s1, 32);
        c2 += __shfl_xor(c2, 16); c2 += __shfl_xor(c2, 32);
        s2 += __shfl_xor(s2, 16); s2 += __shfl_xor(s2, 32);
        c3 += __shfl_xor(c3, 16); c3 += __shfl_xor(c3, 32);
        s3 += __shfl_xor(s3, 16); s3 += __shfl_xor(s3, 32);
        if (q == 0) {
            int j0 = wj * 64 + l15;
            atomicAdd(&dots[2 * mm][j0],      c0);
            atomicAdd(&dots[2 * mm + 1][j0],  s0);
            atomicAdd(&dots[2 * mm][j0 + 16], c1);
            atomicAdd(&dots[2 * mm + 1][j0 + 16], s1);
            atomicAdd(&dots[2 * mm][j0 + 32], c2);
            atomicAdd(&dots[2 * mm + 1][j0 + 32], s2);
            atomicAdd(&dots[2 * mm][j0 + 48], c3);
            atomicAdd(&dots[2 * mm + 1][j0 + 48], s3);
        }

        if (mm < 3) {
            __syncthreads();   // all reads of P_m done -> safe to overwrite
            #pragma unroll
            for (int rr = 0; rr < 4; ++rr) {
                int r0 = wr * 64 + rr * 16 + q * 4;
                float4 di4 = *(const float4*)(diA + r0);
                int slot = (wr * 4 + rr) * 2 + (q >> 1);
                #pragma unroll
                for (int jj = 0; jj < 4; ++jj) {
                    int jloc = wj * 64 + jj * 16 + l15;
                    int slp = slot ^ (jloc & 7);
                    f32x4 W = acc[rr][jj];
                    u32x2 nw;
                    nw.x = pkh2(di4.x * W[0], di4.y * W[1]);
                    nw.y = pkh2(di4.z * W[2], di4.w * W[3]);
                    *(u32x2*)(Zt + jloc * 256 + slp * 8 + (q & 1) * 4) = nw;
                }
            }
            __syncthreads();
        }
    }

    // ---- hoisted epilogue constants: issue before the final barrier ----
    const int h = lane << 2;                          // column quad owned by lane
    float4 w00 = *(const float4*)(w + (size_t)(h + 0) * KD);
    float4 w01 = *(const float4*)(w + (size_t)(h + 0) * KD + 4);
    float4 w10 = *(const float4*)(w + (size_t)(h + 1) * KD);
    float4 w11 = *(const float4*)(w + (size_t)(h + 1) * KD + 4);
    float4 w20 = *(const float4*)(w + (size_t)(h + 2) * KD);
    float4 w21 = *(const float4*)(w + (size_t)(h + 2) * KD + 4);
    float4 w30 = *(const float4*)(w + (size_t)(h + 3) * KD);
    float4 w31 = *(const float4*)(w + (size_t)(h + 3) * KD + 4);
    float4 bb  = *(const float4*)(b + h);
    __syncthreads();

    // ---- fused epilogue, 1-deep pipelined: out = table[deg] + dots·w^T + b ----
    {
        int j = wid;                                  // 16 nodes per wave, stride 8
        int dgc = cnt[j]; dgc = dgc < 255 ? dgc : 255;
        float4 pe = *(const float4*)(table + (size_t)dgc * HID + h);
        for (; j < 128; j += 8) {
            int jn = j + 8;
            float4 pen = {};
            if (jn < 128) {                           // prefetch next node's gather
                int dgn = cnt[jn]; dgn = dgn < 255 ? dgn : 255;
                pen = *(const float4*)(table + (size_t)dgn * HID + h);
            }
            float r0x = dots[0][j], r0y = dots[1][j], r0z = dots[2][j], r0w = dots[3][j];
            float r1x = dots[4][j], r1y = dots[5][j], r1z = dots[6][j], r1w = dots[7][j];
            float o0 = r0x * w00.x + r0y * w00.y + r0z * w00.z + r0w * w00.w +
                       r1x * w01.x + r1y * w01.y + r1z * w01.z + r1w * w01.w;
            float o1 = r0x * w10.x + r0y * w10.y + r0z * w10.z + r0w * w10.w +
                       r1x * w11.x + r1y * w11.y + r1z * w11.z + r1w * w11.w;
            float o2 = r0x * w20.x + r0y * w20.y + r0z * w20.z + r0w * w20.w +
                       r1x * w21.x + r1y * w21.y + r1z * w21.z + r1w * w21.w;
            float o3 = r0x * w30.x + r0y * w30.y + r0z * w30.z + r0w * w30.w +
                       r1x * w31.x + r1y * w31.y + r1z * w31.z + r1w * w31.w;
            f32x4 res = {pe.x + o0 + bb.x, pe.y + o1 + bb.y,
                         pe.z + o2 + bb.z, pe.w + o3 + bb.w};
            size_t node = (size_t)g * NPG + jb + j;
            *(f32x4*)(out + node * HID + h) = res;    // cached store: drain via L2
            pe = pen;
        }
    }
}

extern "C" void kernel_launch(void* const* d_in, const int* in_sizes, int n_in,
                              void* d_out, int out_size, void* d_ws, size_t ws_size,
                              hipStream_t stream) {
    const int* ei      = (const int*)d_in[1];
    const float* table = (const float*)d_in[3];
    const float* rw_w  = (const float*)d_in[4];
    const float* rw_b  = (const float*)d_in[5];
    float* out         = (float*)d_out;

    const int nNodes = in_sizes[2];
    const int nE     = in_sizes[1] / 2;
    const int B      = nNodes / NPG;
    const int epg    = nE / B;

    k_rw2<<<B * 2, 512, 0, stream>>>(ei, epg, nE, table, rw_w, rw_b, out);
}